// Round 7
// baseline (707.174 us; speedup 1.0000x reference)
//
#include <hip/hip_runtime.h>

#define ANG 9
#define BATCH 4
#define CIN 64
#define COUT 64
#define HW 48
#define IN_HW 432
#define KK 81            // 9x9 taps
#define SPOS 2304        // 48*48
#define SPOS4 (SPOS / 4) // 576
#define DDIM 68          // 17 disparities * 4 replicas

typedef __attribute__((ext_vector_type(8))) short short8;
typedef __attribute__((ext_vector_type(4))) float f32x4;

// xvu PACKED (lives in d_out during build): [b][uv][sy 48][cig 8][sx 48][cil 8]
// bf16 — NO shear margins (dx boundary handled per-lane in conv_mfma LOADX).
#define XVP_ROW 3072                      // 8*48*8 elems per sy row
#define XVP_UVSTRIDE (48 * XVP_ROW)       // 147456 elems per (b,uv)
#define XVP_TOTAL_B ((size_t)BATCH * KK * XVP_UVSTRIDE * 2)  // 95,551,488 <= out bytes

// ws layout: [ppart 63.7MB][wt2 663KB][zrow 10KB]
#define PPART_ELEMS (27 * 4 * 64 * 2304)        // 15,925,248 floats
#define WT2_OFF_B ((size_t)PPART_ELEMS * 4)     // 63,700,992
#define WT2_ELEMS (KK * 8 * 64 * 8)             // 331,776
#define ZROW_OFF_B (WT2_OFF_B + (size_t)WT2_ELEMS * 2)
#define ZROW_ELEMS 5120
#define WS_NEEDED (ZROW_OFF_B + (size_t)ZROW_ELEMS * 2)   // ~64.4 MB

__device__ __forceinline__ unsigned short f2bf(float f) {
  unsigned u = __float_as_uint(f);
  u += 0x7fffu + ((u >> 16) & 1u);        // round-to-nearest-even
  return (unsigned short)(u >> 16);
}

// ---------------------------------------------------------------------------
// convert_kernel: x[b][ci][iy][ix] fp32 -> xvu packed bf16 (iy=9*sy+u,
// ix=9*sx+v). One block per (b,u,sy,xc), xc in {0,1,2} (ix row = 3 chunks of
// 144 = 16sx x 9v). LDS 18 KB; no zero margins. Phase 1: lane = ci, wave w
// reads fx=it*4+w; LDS scatter hits all 32 banks. Phase 2: coalesced uint4.
// ---------------------------------------------------------------------------
__global__ __launch_bounds__(256) void convert_kernel(
    const float* __restrict__ x, unsigned short* __restrict__ xvu) {
  __shared__ unsigned short lsm[ANG * 16 * CIN];  // [v][sxl][ci-swizzled] 18KB
  int q  = blockIdx.x;
  int xc = q % 3;
  int sy = (q / 3) % HW;
  int u  = (q / (3 * HW)) % ANG;
  int b  = q / (3 * HW * ANG);
  int iy = sy * ANG + u;
  int t  = threadIdx.x;
  int w  = t >> 6;               // wave id 0..3
  int l  = t & 63;               // lane = ci
  int lg = l >> 3, lr = l & 7;

  const float* px = x + ((size_t)(b * CIN + l) * IN_HW + iy) * IN_HW
                  + xc * 144 + w * 4;
#pragma unroll
  for (int it = 0; it < 9; ++it) {
    float4 f = *(const float4*)(px + it * 16);   // fx = it*4 + w within chunk
    int ix0 = xc * 144 + (it * 4 + w) * 4;
    float fv[4] = {f.x, f.y, f.z, f.w};
#pragma unroll
    for (int k2 = 0; k2 < 4; ++k2) {
      int ix = ix0 + k2;
      int v  = ix % 9;
      int sx = ix / 9;                    // in [16*xc, 16*xc+16)
      int cisw = ((lg ^ (sx & 7)) << 3) | lr;
      lsm[(v * 16 + (sx & 15)) * CIN + cisw] = f2bf(fv[k2]);
    }
  }
  __syncthreads();

  // Phase 2: write [v][cig][sx-chunk] uint4 (8 cil elems) — packed, no margins.
  uint4* dst = (uint4*)xvu;
  size_t base_u4 = (size_t)(b * KK + u * ANG) * (XVP_UVSTRIDE / 8)
                 + (size_t)sy * (XVP_ROW / 8);
  const uint4* ls4 = (const uint4*)lsm;
  for (int s = t; s < 9 * 8 * 16; s += 256) {   // 1152
    int v2  = s >> 7;
    int rem = s & 127;
    int cig = rem >> 4;
    int sxl = rem & 15;
    int sx  = xc * 16 + sxl;
    int cig2 = cig ^ (sx & 7);
    uint4 val = ls4[((v2 * 16 + sxl) * CIN + cig2 * 8) >> 3];
    dst[base_u4 + (size_t)v2 * (XVP_UVSTRIDE / 8) + cig * 48 + sx] = val;
  }
}

// ---------------------------------------------------------------------------
// wprep_kernel: wt2[uv][cig][co][cil] = bf16(w[co][cig*8+cil][uv])
// ---------------------------------------------------------------------------
__global__ __launch_bounds__(256) void wprep_kernel(
    const float* __restrict__ w, unsigned short* __restrict__ wt2) {
  int s   = blockIdx.x * 256 + threadIdx.x;   // < 331776
  int cil = s & 7;
  int co  = (s >> 3) & 63;
  int cig = (s >> 9) & 7;
  int uv  = s >> 12;
  wt2[s] = f2bf(w[((size_t)co * CIN + cig * 8 + cil) * KK + uv]);
}

// ---------------------------------------------------------------------------
// conv_mfma_kernel: K-split x3 implicit GEMM, fragment-major layouts.
// REVERTED to the R4 winner (256 threads, 4 waves, ping-pong depth-1,
// 88 VGPR no-spill). R6 lesson: __launch_bounds__ 2nd arg acts like min
// BLOCKS/CU on this toolchain — (512,4) capped VGPR at 64 and spilled
// (WRITE_SIZE 63->582 MB, 3.3x regression). NEW this round: weight LDS
// double-buffer shrunk from 3-tile groups (48 KB) to 2-tile groups (32 KB)
// -> 4 blocks/CU instead of 3 (LDS-capped; VGPR 88 <= 128 allows 4 waves/EU)
// = 16 waves/CU, +33% TLP to cover the per-group barrier drains. Cost: 14
// barriers vs 10. wt2 LDS-staged (R2 win); packed xvu + predicated shear
// (R4 win); XCD-bijective swizzle, di innermost (R1 win).
// ---------------------------------------------------------------------------
__global__ __launch_bounds__(256, 4) void conv_mfma_kernel(
    const unsigned short* __restrict__ xvu,
    const unsigned short* __restrict__ wt2,
    const unsigned short* __restrict__ zrow,
    float* __restrict__ ppart) {
  __shared__ __align__(16) unsigned short lw[2][2][4096];  // 32 KB

  int raw = blockIdx.x;                  // 1296 = 8 XCDs * 162
  int L   = (raw & 7) * 162 + (raw >> 3);  // bijective: XCD gets contig chunk
  int di  = L % 9;                       // d innermost: 9 di co-resident
  int r1  = L / 9;
  int kc  = r1 % 3;
  int r2  = r1 / 3;
  int mt12 = r2 % 12;
  int b    = r2 / 12;
  int d    = di - 4;

  int tid  = threadIdx.x;
  int wid  = tid >> 6;             // 0..3
  int lane = tid & 63;
  int n16  = lane & 15;
  int kq   = lane >> 4;
  int sy   = mt12 * 4 + wid;       // wave's output row

  int wlane = kq * 512 + n16 * 8;  // lane offset inside a wt2 tile

  f32x4 acc[4][3];
#pragma unroll
  for (int mt = 0; mt < 4; ++mt)
#pragma unroll
    for (int nt = 0; nt < 3; ++nt) acc[mt][nt] = (f32x4){0.f, 0.f, 0.f, 0.f};

  short8 wf[4][2], xfA[3][2], xfB[3][2];
  int s0 = kc * 27;

  // Stage gs consecutive wt2 tiles (gs*8 KB) starting at rel tile base_rel
  // into LDS buffer pb. 4 waves, each stages gs*2 KB = gs*2 x (64 lanes x 16B).
  auto STAGE = [&](int base_rel, int gs, int pb) {
    int base_uv = s0 + base_rel;
    int uvs_lo  = (d > 0) ? (80 - base_uv - (gs - 1)) : base_uv;
    const char* gsrc = (const char*)(wt2 + (size_t)uvs_lo * 4096)
                     + wid * (gs * 2048) + lane * 16;
    char* ldst = (char*)(&lw[pb][0][0]) + wid * (gs * 2048);
#pragma unroll
    for (int i = 0; i < 2 * 2; ++i) {         // gs<=2 -> up to 4 issues
      if (i < gs * 2) {
        __builtin_amdgcn_global_load_lds(
            (const __attribute__((address_space(1))) unsigned int*)(gsrc + i * 1024),
            (__attribute__((address_space(3))) unsigned int*)(ldst + i * 1024),
            16, 0, 0);
      }
    }
  };

  auto LOADW = [&](const unsigned short* lwt) {
#pragma unroll
    for (int mt = 0; mt < 4; ++mt) {
      wf[mt][0] = *(const short8*)(lwt + mt * 128);
      wf[mt][1] = *(const short8*)(lwt + mt * 128 + 2048);
    }
  };

  auto LOADX = [&](int uv, short8 (&xf)[3][2]) {
    int u  = (uv * 57) >> 9;                 // uv/9 for uv<=80
    int v  = uv - u * 9;
    int dy = d * (u - 4), dx = d * (v - 4);
    unsigned syi = (unsigned)(sy - dy);
    const unsigned short* xr = xvu + (size_t)(b * KK + uv) * XVP_UVSTRIDE
                             + (size_t)syi * XVP_ROW + kq * 384;
    int rbad = (syi < 48u) ? 0 : 64;         // wave-uniform row-validity tag
#pragma unroll
    for (int nt = 0; nt < 3; ++nt) {
      int sx  = n16 + nt * 16 - dx;          // [-16, 63]
      bool ok = (unsigned)(sx | rbad) < 48u;
      const unsigned short* p0 = ok ? (xr + sx * 8)        : zrow;
      const unsigned short* p1 = ok ? (xr + sx * 8 + 1536) : zrow;
      xf[nt][0] = *(const short8*)p0;
      xf[nt][1] = *(const short8*)p1;
    }
  };

  auto MF = [&](short8 (&xf)[3][2]) {
    __builtin_amdgcn_s_setprio(1);
#pragma unroll
    for (int mt = 0; mt < 4; ++mt)
#pragma unroll
      for (int nt = 0; nt < 3; ++nt) {
        acc[mt][nt] = __builtin_amdgcn_mfma_f32_16x16x32_bf16(
            wf[mt][0], xf[nt][0], acc[mt][nt], 0, 0, 0);
        acc[mt][nt] = __builtin_amdgcn_mfma_f32_16x16x32_bf16(
            wf[mt][1], xf[nt][1], acc[mt][nt], 0, 0, 0);
      }
    __builtin_amdgcn_s_setprio(0);
  };

  // 14 groups: g=0..12 are 2-tile (tiles 2g,2g+1), g=13 is the 1-tile tail (26).
  STAGE(0, 2, 0);
  LOADX(s0, xfA);
  __syncthreads();                 // vmcnt(0): group 0 staged

#pragma unroll
  for (int g = 0; g < 13; ++g) {
    if (g < 12) STAGE(2 * (g + 1), 2, (g + 1) & 1);  // overlaps this group's MFMAs
    else        STAGE(26, 1, 1);                      // tail tile into buf 1
#pragma unroll
    for (int j = 0; j < 2; ++j) {
      const int idx  = g * 2 + j;           // 0..25, static
      int tloc = (d > 0) ? (1 - j) : j;     // wave-uniform runtime select
      const unsigned short* lwt = &lw[g & 1][0][0] + tloc * 4096 + wlane;
      if ((idx & 1) == 0) {
        LOADX(s0 + idx + 1, xfB);
        LOADW(lwt);
        MF(xfA);
      } else {
        LOADX(s0 + idx + 1, xfA);           // idx=25 loads tile 26 for the tail
        LOADW(lwt);
        MF(xfB);
      }
    }
    __syncthreads();               // publish staged group g+1; waves done with g&1
  }
  {                                 // tail: tile 26 from buf 1 (tloc = 0 either sign)
    const unsigned short* lwt = &lw[1][0][0] + wlane;
    LOADW(lwt);
    MF(xfA);
  }

  // Epilogue: C/D col = n16 -> sp within row; row = kq*4+reg -> co in tile.
  float* pb = ppart + ((size_t)((di * 3 + kc) * 4 + b)) * COUT * SPOS + sy * 48;
#pragma unroll
  for (int mt = 0; mt < 4; ++mt) {
#pragma unroll
    for (int r = 0; r < 4; ++r) {
      int co = mt * 16 + kq * 4 + r;
      float* o = pb + (size_t)co * SPOS;
#pragma unroll
      for (int nt = 0; nt < 3; ++nt) o[nt * 16 + n16] = acc[mt][nt][r];
    }
  }
}

// ---------------------------------------------------------------------------
// expand_kernel (float4): reads 27 partials from ws, sums triples, writes all
// 68 output slices (even-t groups = 0, odd-t = 0.5*(tv[j]+tv[j+1]) x4).
// ---------------------------------------------------------------------------
__global__ __launch_bounds__(256) void expand_kernel(
    const float* __restrict__ ppart, float* __restrict__ out) {
  int p4 = blockIdx.x * 256 + threadIdx.x;   // < 4*64*576 = 147456
  int bc = p4 / SPOS4;
  int s4 = p4 - bc * SPOS4;
  const f32x4* pp = (const f32x4*)ppart;
  f32x4* po = (f32x4*)out;
  f32x4 tv[9];
#pragma unroll
  for (int jj = 0; jj < 9; ++jj) {
    f32x4 a = pp[(size_t)(jj * 3 + 0) * 147456 + p4];
    f32x4 c = pp[(size_t)(jj * 3 + 1) * 147456 + p4];
    f32x4 e = pp[(size_t)(jj * 3 + 2) * 147456 + p4];
    tv[jj] = a + c + e;
  }
  size_t base = (size_t)bc * DDIM * SPOS4 + s4;
  f32x4 z = {0.f, 0.f, 0.f, 0.f};
#pragma unroll
  for (int jj = 0; jj < 9; ++jj) {
    size_t o = base + (size_t)(8 * jj) * SPOS4;
    po[o] = z; po[o + SPOS4] = z; po[o + 2 * SPOS4] = z; po[o + 3 * SPOS4] = z;
  }
#pragma unroll
  for (int jj = 0; jj < 8; ++jj) {
    f32x4 v = 0.5f * (tv[jj] + tv[jj + 1]);
    size_t o = base + (size_t)(8 * jj + 4) * SPOS4;
    po[o] = v; po[o + SPOS4] = v; po[o + 2 * SPOS4] = v; po[o + 3 * SPOS4] = v;
  }
}

// ---------------------------------------------------------------------------
// Fallback path (tiny ws): R1 fp32 conv stashing into d_out even slices +
// in-place expand.
// ---------------------------------------------------------------------------
__global__ __launch_bounds__(256, 4) void conv_kernel(
    const float* __restrict__ x, const float* __restrict__ w,
    float* __restrict__ out) {
  __shared__ float lw[COUT * KK];
  __shared__ float lx[KK * 32];
  int bi  = blockIdx.x;
  int oxt = bi % 3;
  int oy2 = (bi / 3) % 24;
  int b   = (bi / 72) % BATCH;
  int di  = bi / 288;
  int d   = di - 4;
  int dil, pad;
  if (d < 0)       { dil = (-d) * ANG + 1; pad = (-d) * 36; }
  else if (d == 0) { dil = 1;              pad = 0; }
  else             { dil = d * ANG - 1;    pad = d * 36 - 8; }
  int t = threadIdx.x, tx = t & 15, ty = t >> 4;
  float acc[4][2] = {};
  const float* xb = x + (size_t)b * CIN * IN_HW * IN_HW;
  for (int ci = 0; ci < CIN; ++ci) {
    __syncthreads();
    for (int s = t; s < COUT * KK; s += 256) {
      int co = s / KK, k = s - co * KK;
      lw[s] = w[((size_t)co * CIN + ci) * KK + k];
    }
    const float* xc = xb + (size_t)ci * IN_HW * IN_HW;
    for (int s = t; s < KK * 32; s += 256) {
      int k = s >> 5, rem = s & 31, r = rem >> 4, c = rem & 15;
      int ky = k / ANG, kx = k - ky * ANG;
      int iy = (oy2 * 2 + r) * ANG - pad + ky * dil;
      int ix = (oxt * 16 + c) * ANG - pad + kx * dil;
      float vv = 0.f;
      if ((unsigned)iy < IN_HW && (unsigned)ix < IN_HW) vv = xc[iy * IN_HW + ix];
      lx[s] = vv;
    }
    __syncthreads();
    const float* lwp = lw + ty * 4 * KK;
#pragma unroll 9
    for (int k = 0; k < KK; ++k) {
      float x0 = lx[k * 32 + tx], x1 = lx[k * 32 + 16 + tx];
      float w0 = lwp[k], w1 = lwp[k + KK], w2 = lwp[k + 2 * KK], w3 = lwp[k + 3 * KK];
      acc[0][0] += w0 * x0; acc[0][1] += w0 * x1;
      acc[1][0] += w1 * x0; acc[1][1] += w1 * x1;
      acc[2][0] += w2 * x0; acc[2][1] += w2 * x1;
      acc[3][0] += w3 * x0; acc[3][1] += w3 * x1;
    }
  }
  int oy = oy2 * 2, ox = oxt * 16 + tx;
#pragma unroll
  for (int j = 0; j < 4; ++j) {
    int co = ty * 4 + j;
    size_t base = (((size_t)(b * COUT + co) * DDIM) + 8 * di) * SPOS;
    out[base + (size_t)oy * HW + ox]       = acc[j][0];
    out[base + (size_t)(oy + 1) * HW + ox] = acc[j][1];
  }
}

__global__ __launch_bounds__(256) void expand_inplace_kernel(float* __restrict__ out) {
  int p  = blockIdx.x * 256 + threadIdx.x;
  int bc = p / SPOS;
  int s  = p - bc * SPOS;
  size_t base = (size_t)bc * DDIM * SPOS + s;
  float tv[9];
#pragma unroll
  for (int jj = 0; jj < 9; ++jj) tv[jj] = out[base + (size_t)(8 * jj) * SPOS];
#pragma unroll
  for (int jj = 0; jj < 9; ++jj) {
    size_t o = base + (size_t)(8 * jj) * SPOS;
    out[o] = 0.f; out[o + SPOS] = 0.f; out[o + 2 * SPOS] = 0.f; out[o + 3 * SPOS] = 0.f;
  }
#pragma unroll
  for (int jj = 0; jj < 8; ++jj) {
    float v = 0.5f * (tv[jj] + tv[jj + 1]);
    size_t o = base + (size_t)(8 * jj + 4) * SPOS;
    out[o] = v; out[o + SPOS] = v; out[o + 2 * SPOS] = v; out[o + 3 * SPOS] = v;
  }
}

extern "C" void kernel_launch(void* const* d_in, const int* in_sizes, int n_in,
                              void* d_out, int out_size, void* d_ws, size_t ws_size,
                              hipStream_t stream) {
  const float* x = (const float*)d_in[0];   // [4, 64, 432, 432]
  const float* w = (const float*)d_in[1];   // [64, 64, 9, 9]
  float* out = (float*)d_out;               // [4, 64, 68, 48, 48]

  if (ws_size >= WS_NEEDED) {
    float* ppart = (float*)d_ws;
    unsigned short* wt2  = (unsigned short*)((char*)d_ws + WT2_OFF_B);
    unsigned short* zrow = (unsigned short*)((char*)d_ws + ZROW_OFF_B);
    unsigned short* xvu  = (unsigned short*)d_out;   // build area inside d_out

    hipMemsetAsync(zrow, 0, ZROW_ELEMS * 2, stream);
    wprep_kernel<<<dim3(WT2_ELEMS / 256), dim3(256), 0, stream>>>(w, wt2);
    convert_kernel<<<dim3(BATCH * ANG * HW * 3), dim3(256), 0, stream>>>(x, xvu);
    conv_mfma_kernel<<<dim3(9 * 4 * 12 * 3), dim3(256), 0, stream>>>(xvu, wt2, zrow, ppart);
    expand_kernel<<<dim3((BATCH * COUT * SPOS4) / 256), dim3(256), 0, stream>>>(ppart, out);
  } else {
    conv_kernel<<<dim3(9 * 4 * 24 * 3), dim3(256), 0, stream>>>(x, w, out);
    expand_inplace_kernel<<<dim3((BATCH * COUT * SPOS) / 256), dim3(256), 0, stream>>>(out);
  }
}

// Round 8
// 426.994 us; speedup vs baseline: 1.6562x; 1.6562x over previous
//
#include <hip/hip_runtime.h>

#define ANG 9
#define BATCH 4
#define CIN 64
#define COUT 64
#define HW 48
#define IN_HW 432
#define KK 81            // 9x9 taps
#define SPOS 2304        // 48*48
#define SPOS4 (SPOS / 4) // 576
#define DDIM 68          // 17 disparities * 4 replicas

typedef __attribute__((ext_vector_type(8))) short short8;
typedef __attribute__((ext_vector_type(4))) float f32x4;

// xvu PACKED (lives in d_out during build): [b][uv][sy 48][cig 8][sx 48][cil 8]
// bf16 — NO shear margins (dx boundary handled per-lane in conv_mfma LOADX).
#define XVP_ROW 3072                      // 8*48*8 elems per sy row
#define XVP_UVSTRIDE (48 * XVP_ROW)       // 147456 elems per (b,uv)
#define XVP_TOTAL_B ((size_t)BATCH * KK * XVP_UVSTRIDE * 2)  // 95,551,488 <= out bytes

// ws layout: [ppart 63.7MB][wt2 663KB][zrow 10KB]
#define PPART_ELEMS (27 * 4 * 64 * 2304)        // 15,925,248 floats
#define WT2_OFF_B ((size_t)PPART_ELEMS * 4)     // 63,700,992
#define WT2_ELEMS (KK * 8 * 64 * 8)             // 331,776
#define ZROW_OFF_B (WT2_OFF_B + (size_t)WT2_ELEMS * 2)
#define ZROW_ELEMS 5120
#define WS_NEEDED (ZROW_OFF_B + (size_t)ZROW_ELEMS * 2)   // ~64.4 MB

__device__ __forceinline__ unsigned short f2bf(float f) {
  unsigned u = __float_as_uint(f);
  u += 0x7fffu + ((u >> 16) & 1u);        // round-to-nearest-even
  return (unsigned short)(u >> 16);
}

// ---------------------------------------------------------------------------
// convert_kernel: x[b][ci][iy][ix] fp32 -> xvu packed bf16 (iy=9*sy+u,
// ix=9*sx+v). One block per (b,u,sy,xc), xc in {0,1,2} (ix row = 3 chunks of
// 144 = 16sx x 9v). LDS 18 KB; no zero margins. Phase 1: lane = ci, wave w
// reads fx=it*4+w; LDS scatter hits all 32 banks. Phase 2: coalesced uint4.
// ---------------------------------------------------------------------------
__global__ __launch_bounds__(256) void convert_kernel(
    const float* __restrict__ x, unsigned short* __restrict__ xvu) {
  __shared__ unsigned short lsm[ANG * 16 * CIN];  // [v][sxl][ci-swizzled] 18KB
  int q  = blockIdx.x;
  int xc = q % 3;
  int sy = (q / 3) % HW;
  int u  = (q / (3 * HW)) % ANG;
  int b  = q / (3 * HW * ANG);
  int iy = sy * ANG + u;
  int t  = threadIdx.x;
  int w  = t >> 6;               // wave id 0..3
  int l  = t & 63;               // lane = ci
  int lg = l >> 3, lr = l & 7;

  const float* px = x + ((size_t)(b * CIN + l) * IN_HW + iy) * IN_HW
                  + xc * 144 + w * 4;
#pragma unroll
  for (int it = 0; it < 9; ++it) {
    float4 f = *(const float4*)(px + it * 16);   // fx = it*4 + w within chunk
    int ix0 = xc * 144 + (it * 4 + w) * 4;
    float fv[4] = {f.x, f.y, f.z, f.w};
#pragma unroll
    for (int k2 = 0; k2 < 4; ++k2) {
      int ix = ix0 + k2;
      int v  = ix % 9;
      int sx = ix / 9;                    // in [16*xc, 16*xc+16)
      int cisw = ((lg ^ (sx & 7)) << 3) | lr;
      lsm[(v * 16 + (sx & 15)) * CIN + cisw] = f2bf(fv[k2]);
    }
  }
  __syncthreads();

  // Phase 2: write [v][cig][sx-chunk] uint4 (8 cil elems) — packed, no margins.
  uint4* dst = (uint4*)xvu;
  size_t base_u4 = (size_t)(b * KK + u * ANG) * (XVP_UVSTRIDE / 8)
                 + (size_t)sy * (XVP_ROW / 8);
  const uint4* ls4 = (const uint4*)lsm;
  for (int s = t; s < 9 * 8 * 16; s += 256) {   // 1152
    int v2  = s >> 7;
    int rem = s & 127;
    int cig = rem >> 4;
    int sxl = rem & 15;
    int sx  = xc * 16 + sxl;
    int cig2 = cig ^ (sx & 7);
    uint4 val = ls4[((v2 * 16 + sxl) * CIN + cig2 * 8) >> 3];
    dst[base_u4 + (size_t)v2 * (XVP_UVSTRIDE / 8) + cig * 48 + sx] = val;
  }
}

// ---------------------------------------------------------------------------
// wprep_kernel: wt2[uv][cig][co][cil] = bf16(w[co][cig*8+cil][uv])
// ---------------------------------------------------------------------------
__global__ __launch_bounds__(256) void wprep_kernel(
    const float* __restrict__ w, unsigned short* __restrict__ wt2) {
  int s   = blockIdx.x * 256 + threadIdx.x;   // < 331776
  int cil = s & 7;
  int co  = (s >> 3) & 63;
  int cig = (s >> 9) & 7;
  int uv  = s >> 12;
  wt2[s] = f2bf(w[((size_t)co * CIN + cig * 8 + cil) * KK + uv]);
}

// ---------------------------------------------------------------------------
// conv_mfma_kernel: K-split x3 implicit GEMM, fragment-major layouts.
// Config pinned to the proven no-spill point: 256 threads, (256,2), 48 KB
// lw[2][3][4096]. R6/R7 lesson: ANY occupancy-raising hint (2nd arg >= 4 or
// smaller LDS) makes the allocator clamp to 64 VGPR and spill (WRITE_SIZE
// 63 -> 580-700 MB, 3.3x regression). NEW this round (T3+T4): per-group
// __syncthreads (which drains vmcnt(0), killing the xf pipeline every 3
// steps) is replaced by counted `s_waitcnt vmcnt(12)` + raw s_barrier, and
// xf deepened to a 3-buffer depth-2 rotation. Count accounting: per group,
// issue order = STAGE[6] -> 3x LOADX[6]; MF(j=2) already forces vmcnt<=12,
// so vmcnt(12) at the barrier retires the stage (oldest in FIFO) while the
// two newest xf batches stay in flight ACROSS the barrier (~2 MF-blocks of
// latency cover). Memory-clobber asm pins vmem issue order around STAGE and
// the barrier. Buffer-reuse safe: stage g+1 overwrites the LDS buffer last
// read in group g-1, two barriers upstream.
// ---------------------------------------------------------------------------
__global__ __launch_bounds__(256, 2) void conv_mfma_kernel(
    const unsigned short* __restrict__ xvu,
    const unsigned short* __restrict__ wt2,
    const unsigned short* __restrict__ zrow,
    float* __restrict__ ppart) {
  __shared__ __align__(16) unsigned short lw[2][3][4096];  // 48 KB

  int raw = blockIdx.x;                  // 1296 = 8 XCDs * 162
  int L   = (raw & 7) * 162 + (raw >> 3);  // bijective: XCD gets contig chunk
  int di  = L % 9;                       // d innermost: 9 di co-resident
  int r1  = L / 9;
  int kc  = r1 % 3;
  int r2  = r1 / 3;
  int mt12 = r2 % 12;
  int b    = r2 / 12;
  int d    = di - 4;

  int tid  = threadIdx.x;
  int wid  = tid >> 6;             // 0..3
  int lane = tid & 63;
  int n16  = lane & 15;
  int kq   = lane >> 4;
  int sy   = mt12 * 4 + wid;       // wave's output row

  int wlane = kq * 512 + n16 * 8;  // lane offset inside a wt2 tile

  f32x4 acc[4][3];
#pragma unroll
  for (int mt = 0; mt < 4; ++mt)
#pragma unroll
    for (int nt = 0; nt < 3; ++nt) acc[mt][nt] = (f32x4){0.f, 0.f, 0.f, 0.f};

  short8 wf[4][2];
  short8 xf[3][3][2];              // 3-deep rotation of x fragments
  int s0 = kc * 27;

  // Stage 3 consecutive wt2 tiles (24 KB) of group g into LDS buffer pb.
  // 4 waves, each stages a 6 KB slice: 6 issues x (64 lanes x 16 B).
  auto STAGE = [&](int g, int pb) {
    int base_uv = s0 + g * 3;
    int uvs_lo  = (d > 0) ? (78 - base_uv) : base_uv;
    const char* gsrc = (const char*)(wt2 + (size_t)uvs_lo * 4096)
                     + wid * 6144 + lane * 16;
    char* ldst = (char*)(&lw[pb][0][0]) + wid * 6144;
#pragma unroll
    for (int i = 0; i < 6; ++i) {
      __builtin_amdgcn_global_load_lds(
          (const __attribute__((address_space(1))) unsigned int*)(gsrc + i * 1024),
          (__attribute__((address_space(3))) unsigned int*)(ldst + i * 1024),
          16, 0, 0);
    }
    asm volatile("" ::: "memory");   // pin: later vmem must not hoist above stage
  };

  auto LOADW = [&](const unsigned short* lwt) {
#pragma unroll
    for (int mt = 0; mt < 4; ++mt) {
      wf[mt][0] = *(const short8*)(lwt + mt * 128);
      wf[mt][1] = *(const short8*)(lwt + mt * 128 + 2048);
    }
  };

  auto LOADX = [&](int uv, short8 (&f)[3][2]) {
    int u  = (uv * 57) >> 9;                 // uv/9 for uv<=80
    int v  = uv - u * 9;
    int dy = d * (u - 4), dx = d * (v - 4);
    unsigned syi = (unsigned)(sy - dy);
    const unsigned short* xr = xvu + (size_t)(b * KK + uv) * XVP_UVSTRIDE
                             + (size_t)syi * XVP_ROW + kq * 384;
    int rbad = (syi < 48u) ? 0 : 64;         // wave-uniform row-validity tag
#pragma unroll
    for (int nt = 0; nt < 3; ++nt) {
      int sx  = n16 + nt * 16 - dx;          // [-16, 63]
      bool ok = (unsigned)(sx | rbad) < 48u;
      const unsigned short* p0 = ok ? (xr + sx * 8)        : zrow;
      const unsigned short* p1 = ok ? (xr + sx * 8 + 1536) : zrow;
      f[nt][0] = *(const short8*)p0;
      f[nt][1] = *(const short8*)p1;
    }
  };

  auto MF = [&](short8 (&f)[3][2]) {
    __builtin_amdgcn_s_setprio(1);
#pragma unroll
    for (int mt = 0; mt < 4; ++mt)
#pragma unroll
      for (int nt = 0; nt < 3; ++nt) {
        acc[mt][nt] = __builtin_amdgcn_mfma_f32_16x16x32_bf16(
            wf[mt][0], f[nt][0], acc[mt][nt], 0, 0, 0);
        acc[mt][nt] = __builtin_amdgcn_mfma_f32_16x16x32_bf16(
            wf[mt][1], f[nt][1], acc[mt][nt], 0, 0, 0);
      }
    __builtin_amdgcn_s_setprio(0);
  };

  // Counted-vmcnt barrier: stage (oldest) retired, newest 2 xf batches live.
  auto GBAR = [&]() {
    asm volatile("s_waitcnt vmcnt(12)" ::: "memory");
    __builtin_amdgcn_s_barrier();
    asm volatile("" ::: "memory");   // pin: next group's LDS reads stay below
  };

  STAGE(0, 0);
  LOADX(s0 + 0, xf[0]);            // depth-2 prologue
  LOADX(s0 + 1, xf[1]);
  GBAR();                          // retires stage; xf0/xf1 stay in flight

#pragma unroll
  for (int g = 0; g < 9; ++g) {
    if (g < 8) STAGE(g + 1, (g + 1) & 1);   // overlaps with this group's MFMAs
#pragma unroll
    for (int j = 0; j < 3; ++j) {
      const int idx = g * 3 + j;            // 0..26, compile-time
      int tloc = (d > 0) ? (2 - j) : j;     // wave-uniform runtime select
      const unsigned short* lwt = &lw[g & 1][0][0] + tloc * 4096 + wlane;
      if (idx < 25) LOADX(s0 + idx + 2, xf[(idx + 2) % 3]);  // depth-2 issue
      LOADW(lwt);
      MF(xf[idx % 3]);
    }
    GBAR();                        // publish staged group g+1; xf pipe survives
  }

  // Epilogue: C/D col = n16 -> sp within row; row = kq*4+reg -> co in tile.
  float* pb = ppart + ((size_t)((di * 3 + kc) * 4 + b)) * COUT * SPOS + sy * 48;
#pragma unroll
  for (int mt = 0; mt < 4; ++mt) {
#pragma unroll
    for (int r = 0; r < 4; ++r) {
      int co = mt * 16 + kq * 4 + r;
      float* o = pb + (size_t)co * SPOS;
#pragma unroll
      for (int nt = 0; nt < 3; ++nt) o[nt * 16 + n16] = acc[mt][nt][r];
    }
  }
}

// ---------------------------------------------------------------------------
// expand_kernel (float4): reads 27 partials from ws, sums triples, writes all
// 68 output slices (even-t groups = 0, odd-t = 0.5*(tv[j]+tv[j+1]) x4).
// ---------------------------------------------------------------------------
__global__ __launch_bounds__(256) void expand_kernel(
    const float* __restrict__ ppart, float* __restrict__ out) {
  int p4 = blockIdx.x * 256 + threadIdx.x;   // < 4*64*576 = 147456
  int bc = p4 / SPOS4;
  int s4 = p4 - bc * SPOS4;
  const f32x4* pp = (const f32x4*)ppart;
  f32x4* po = (f32x4*)out;
  f32x4 tv[9];
#pragma unroll
  for (int jj = 0; jj < 9; ++jj) {
    f32x4 a = pp[(size_t)(jj * 3 + 0) * 147456 + p4];
    f32x4 c = pp[(size_t)(jj * 3 + 1) * 147456 + p4];
    f32x4 e = pp[(size_t)(jj * 3 + 2) * 147456 + p4];
    tv[jj] = a + c + e;
  }
  size_t base = (size_t)bc * DDIM * SPOS4 + s4;
  f32x4 z = {0.f, 0.f, 0.f, 0.f};
#pragma unroll
  for (int jj = 0; jj < 9; ++jj) {
    size_t o = base + (size_t)(8 * jj) * SPOS4;
    po[o] = z; po[o + SPOS4] = z; po[o + 2 * SPOS4] = z; po[o + 3 * SPOS4] = z;
  }
#pragma unroll
  for (int jj = 0; jj < 8; ++jj) {
    f32x4 v = 0.5f * (tv[jj] + tv[jj + 1]);
    size_t o = base + (size_t)(8 * jj + 4) * SPOS4;
    po[o] = v; po[o + SPOS4] = v; po[o + 2 * SPOS4] = v; po[o + 3 * SPOS4] = v;
  }
}

// ---------------------------------------------------------------------------
// Fallback path (tiny ws): R1 fp32 conv stashing into d_out even slices +
// in-place expand.
// ---------------------------------------------------------------------------
__global__ __launch_bounds__(256, 4) void conv_kernel(
    const float* __restrict__ x, const float* __restrict__ w,
    float* __restrict__ out) {
  __shared__ float lw[COUT * KK];
  __shared__ float lx[KK * 32];
  int bi  = blockIdx.x;
  int oxt = bi % 3;
  int oy2 = (bi / 3) % 24;
  int b   = (bi / 72) % BATCH;
  int di  = bi / 288;
  int d   = di - 4;
  int dil, pad;
  if (d < 0)       { dil = (-d) * ANG + 1; pad = (-d) * 36; }
  else if (d == 0) { dil = 1;              pad = 0; }
  else             { dil = d * ANG - 1;    pad = d * 36 - 8; }
  int t = threadIdx.x, tx = t & 15, ty = t >> 4;
  float acc[4][2] = {};
  const float* xb = x + (size_t)b * CIN * IN_HW * IN_HW;
  for (int ci = 0; ci < CIN; ++ci) {
    __syncthreads();
    for (int s = t; s < COUT * KK; s += 256) {
      int co = s / KK, k = s - co * KK;
      lw[s] = w[((size_t)co * CIN + ci) * KK + k];
    }
    const float* xc = xb + (size_t)ci * IN_HW * IN_HW;
    for (int s = t; s < KK * 32; s += 256) {
      int k = s >> 5, rem = s & 31, r = rem >> 4, c = rem & 15;
      int ky = k / ANG, kx = k - ky * ANG;
      int iy = (oy2 * 2 + r) * ANG - pad + ky * dil;
      int ix = (oxt * 16 + c) * ANG - pad + kx * dil;
      float vv = 0.f;
      if ((unsigned)iy < IN_HW && (unsigned)ix < IN_HW) vv = xc[iy * IN_HW + ix];
      lx[s] = vv;
    }
    __syncthreads();
    const float* lwp = lw + ty * 4 * KK;
#pragma unroll 9
    for (int k = 0; k < KK; ++k) {
      float x0 = lx[k * 32 + tx], x1 = lx[k * 32 + 16 + tx];
      float w0 = lwp[k], w1 = lwp[k + KK], w2 = lwp[k + 2 * KK], w3 = lwp[k + 3 * KK];
      acc[0][0] += w0 * x0; acc[0][1] += w0 * x1;
      acc[1][0] += w1 * x0; acc[1][1] += w1 * x1;
      acc[2][0] += w2 * x0; acc[2][1] += w2 * x1;
      acc[3][0] += w3 * x0; acc[3][1] += w3 * x1;
    }
  }
  int oy = oy2 * 2, ox = oxt * 16 + tx;
#pragma unroll
  for (int j = 0; j < 4; ++j) {
    int co = ty * 4 + j;
    size_t base = (((size_t)(b * COUT + co) * DDIM) + 8 * di) * SPOS;
    out[base + (size_t)oy * HW + ox]       = acc[j][0];
    out[base + (size_t)(oy + 1) * HW + ox] = acc[j][1];
  }
}

__global__ __launch_bounds__(256) void expand_inplace_kernel(float* __restrict__ out) {
  int p  = blockIdx.x * 256 + threadIdx.x;
  int bc = p / SPOS;
  int s  = p - bc * SPOS;
  size_t base = (size_t)bc * DDIM * SPOS + s;
  float tv[9];
#pragma unroll
  for (int jj = 0; jj < 9; ++jj) tv[jj] = out[base + (size_t)(8 * jj) * SPOS];
#pragma unroll
  for (int jj = 0; jj < 9; ++jj) {
    size_t o = base + (size_t)(8 * jj) * SPOS;
    out[o] = 0.f; out[o + SPOS] = 0.f; out[o + 2 * SPOS] = 0.f; out[o + 3 * SPOS] = 0.f;
  }
#pragma unroll
  for (int jj = 0; jj < 8; ++jj) {
    float v = 0.5f * (tv[jj] + tv[jj + 1]);
    size_t o = base + (size_t)(8 * jj + 4) * SPOS;
    out[o] = v; out[o + SPOS] = v; out[o + 2 * SPOS] = v; out[o + 3 * SPOS] = v;
  }
}

extern "C" void kernel_launch(void* const* d_in, const int* in_sizes, int n_in,
                              void* d_out, int out_size, void* d_ws, size_t ws_size,
                              hipStream_t stream) {
  const float* x = (const float*)d_in[0];   // [4, 64, 432, 432]
  const float* w = (const float*)d_in[1];   // [64, 64, 9, 9]
  float* out = (float*)d_out;               // [4, 64, 68, 48, 48]

  if (ws_size >= WS_NEEDED) {
    float* ppart = (float*)d_ws;
    unsigned short* wt2  = (unsigned short*)((char*)d_ws + WT2_OFF_B);
    unsigned short* zrow = (unsigned short*)((char*)d_ws + ZROW_OFF_B);
    unsigned short* xvu  = (unsigned short*)d_out;   // build area inside d_out

    hipMemsetAsync(zrow, 0, ZROW_ELEMS * 2, stream);
    wprep_kernel<<<dim3(WT2_ELEMS / 256), dim3(256), 0, stream>>>(w, wt2);
    convert_kernel<<<dim3(BATCH * ANG * HW * 3), dim3(256), 0, stream>>>(x, xvu);
    conv_mfma_kernel<<<dim3(9 * 4 * 12 * 3), dim3(256), 0, stream>>>(xvu, wt2, zrow, ppart);
    expand_kernel<<<dim3((BATCH * COUT * SPOS4) / 256), dim3(256), 0, stream>>>(ppart, out);
  } else {
    conv_kernel<<<dim3(9 * 4 * 24 * 3), dim3(256), 0, stream>>>(x, w, out);
    expand_inplace_kernel<<<dim3((BATCH * COUT * SPOS) / 256), dim3(256), 0, stream>>>(out);
  }
}